// Round 3
// baseline (1040.039 us; speedup 1.0000x reference)
//
#include <hip/hip_runtime.h>
#include <math.h>

#define F_IN 128
#define HID  16
#define NCLS 10
#define BS   128   // nodes per bucket (pass-1/2 binning); must be pow2

// ---------------- int degree histogram ----------------
__global__ void k_hist(const int* __restrict__ col, int* __restrict__ cnt, int E) {
    int t = blockIdx.x * blockDim.x + threadIdx.x;
    if (t < E) atomicAdd(&cnt[col[t]], 1);
}

__global__ void k_dinv(const int* __restrict__ cnt, float* __restrict__ dinv, int N) {
    int t = blockIdx.x * blockDim.x + threadIdx.x;
    if (t < N) dinv[t] = rsqrtf((float)cnt[t] + 1.0f);   // +1 self loop
}

// ---------------- xw_s = dinv[n] * (x @ W1)  (128 -> 16) ----------------
__global__ void k_xw(const float* __restrict__ x, const float* __restrict__ W1,
                     const float* __restrict__ dinv, float* __restrict__ xws, int N) {
    __shared__ float Ws[F_IN * HID];
    __shared__ float xs[16 * (F_IN + 1)];
    int t = threadIdx.x;
    for (int i = t; i < F_IN * HID; i += 256) Ws[i] = W1[i];
    int base = blockIdx.x * 16;
    for (int i = t; i < 16 * F_IN; i += 256) {
        int n = i >> 7, k = i & (F_IN - 1);
        xs[n * (F_IN + 1) + k] = (base + n < N) ? x[(size_t)(base + n) * F_IN + k] : 0.f;
    }
    __syncthreads();
    int n = t >> 4, h = t & 15;
    if (base + n >= N) return;
    const float* xr = xs + n * (F_IN + 1);
    float acc = 0.f;
    #pragma unroll
    for (int k = 0; k < F_IN; ++k) acc += xr[k] * Ws[k * HID + h];
    xws[(size_t)(base + n) * HID + h] = dinv[base + n] * acc;
}

// ---------------- exclusive scan over cnt -> off ----------------
__global__ void k_scanA(const int* __restrict__ cnt, int* __restrict__ off,
                        int* __restrict__ bsum, int N) {
    __shared__ int s[256];
    int b = blockIdx.x, t = threadIdx.x;
    int base = b * 1024 + t * 4;
    int v[4], sum = 0;
    #pragma unroll
    for (int i = 0; i < 4; ++i) { int idx = base + i; v[i] = (idx < N) ? cnt[idx] : 0; sum += v[i]; }
    s[t] = sum;
    __syncthreads();
    for (int ofs = 1; ofs < 256; ofs <<= 1) {
        int val = 0;
        if (t >= ofs) val = s[t - ofs];
        __syncthreads();
        if (t >= ofs) s[t] += val;
        __syncthreads();
    }
    int excl = s[t] - sum;
    if (t == 255) bsum[b] = s[255];
    int run = excl;
    #pragma unroll
    for (int i = 0; i < 4; ++i) { int idx = base + i; if (idx < N) off[idx] = run; run += v[i]; }
}

__global__ void k_scanB(int* __restrict__ bsum, int nb) {
    __shared__ int s[128];
    int t = threadIdx.x;
    int v = (t < nb) ? bsum[t] : 0;
    s[t] = v;
    __syncthreads();
    for (int ofs = 1; ofs < 128; ofs <<= 1) {
        int val = 0;
        if (t >= ofs) val = s[t - ofs];
        __syncthreads();
        if (t >= ofs) s[t] += val;
        __syncthreads();
    }
    if (t < nb) bsum[t] = s[t] - v;   // exclusive
}

__global__ void k_scanC(int* __restrict__ off, const int* __restrict__ bsum, int N, int E) {
    int i = blockIdx.x * blockDim.x + threadIdx.x;
    if (i < N) off[i] += bsum[i >> 10];
    if (i == 0) off[N] = E;
}

// ---------------- pass 1: bin edges by target bucket (frontier writes) --------
// packed = (row << 7) | (col & 127); bucket region base = off[bucket*BS]
__global__ void k_bin(const int* __restrict__ row, const int* __restrict__ col,
                      const int* __restrict__ off, int* __restrict__ cur,
                      unsigned int* __restrict__ pairs, int E) {
    int e = blockIdx.x * blockDim.x + threadIdx.x;
    if (e >= E) return;
    int c = col[e];
    int b = c >> 7;
    int p = off[b << 7] + atomicAdd(&cur[b], 1);
    pairs[p] = ((unsigned int)row[e] << 7) | (unsigned int)(c & (BS - 1));
}

// ---------------- pass 2: per-bucket place into CSR (LDS cursors) ----------------
__global__ void k_place(const unsigned int* __restrict__ pairs, const int* __restrict__ off,
                        int* __restrict__ srow, int N, int E) {
    __shared__ int so[BS];
    __shared__ int cu[BS];
    int b = blockIdx.x, t = threadIdx.x;
    int cbase = b << 7;
    int nend = min(cbase + BS, N);
    if (t < BS) {
        so[t] = (cbase + t < N) ? off[cbase + t] : 0;
        cu[t] = 0;
    }
    __syncthreads();
    int pstart = off[cbase];
    int pend = (nend == N) ? E : off[nend];
    for (int i = pstart + t; i < pend; i += blockDim.x) {
        unsigned int v = pairs[i];
        int cl = v & (BS - 1);
        int r = (int)(v >> 7);
        int p = so[cl] + atomicAdd(&cu[cl], 1);
        srow[p] = r;
    }
}

// ---------------- layer-1 pull-gather: hs = dinv * relu(dinv*(sum) + b1) --------
__global__ void k_agg1(const float* __restrict__ xws, const int* __restrict__ off,
                       const int* __restrict__ srow, const float* __restrict__ dinv,
                       const float* __restrict__ b1, float* __restrict__ hs, int N) {
    int n = (blockIdx.x * blockDim.x + threadIdx.x) >> 4;
    int l = threadIdx.x & 15;
    if (n >= N) return;
    int s = off[n], e = off[n + 1];
    float acc = xws[(size_t)n * HID + l];   // self loop (already dinv-scaled)
    int i = s;
    for (; i + 3 < e; i += 4) {
        int r0 = srow[i], r1 = srow[i + 1], r2 = srow[i + 2], r3 = srow[i + 3];
        acc += xws[r0 * HID + l] + xws[r1 * HID + l] + xws[r2 * HID + l] + xws[r3 * HID + l];
    }
    for (; i < e; ++i) acc += xws[srow[i] * HID + l];
    float d = dinv[n];
    float h = d * acc + b1[l];
    h = h > 0.f ? h : 0.f;
    hs[(size_t)n * HID + l] = d * h;
}

// ---------------- layer-2 pull-gather + fused W2/b2/log_softmax ----------------
__global__ void k_agg2(const float* __restrict__ hs, const int* __restrict__ off,
                       const int* __restrict__ srow, const float* __restrict__ dinv,
                       const float* __restrict__ W2, const float* __restrict__ b2,
                       float* __restrict__ out, int N) {
    __shared__ float gs[16][17];
    __shared__ float W2s[HID * NCLS];
    __shared__ float b2s[NCLS];
    int t = threadIdx.x;
    if (t < HID * NCLS) W2s[t] = W2[t];
    if (t < NCLS) b2s[t] = b2[t];
    int grp = t >> 4, l = t & 15;
    int n = blockIdx.x * 16 + grp;
    float g = 0.f;
    if (n < N) {
        int s = off[n], e = off[n + 1];
        float acc = hs[(size_t)n * HID + l];
        int i = s;
        for (; i + 3 < e; i += 4) {
            int r0 = srow[i], r1 = srow[i + 1], r2 = srow[i + 2], r3 = srow[i + 3];
            acc += hs[r0 * HID + l] + hs[r1 * HID + l] + hs[r2 * HID + l] + hs[r3 * HID + l];
        }
        for (; i < e; ++i) acc += hs[srow[i] * HID + l];
        g = dinv[n] * acc;
    }
    gs[grp][l] = g;
    __syncthreads();
    if (t < 16) {
        int n2 = blockIdx.x * 16 + t;
        if (n2 < N) {
            float v[NCLS];
            float m = -INFINITY;
            #pragma unroll
            for (int c = 0; c < NCLS; ++c) {
                float a = b2s[c];
                #pragma unroll
                for (int j = 0; j < HID; ++j) a += gs[t][j] * W2s[j * NCLS + c];
                v[c] = a;
                m = fmaxf(m, a);
            }
            float ssum = 0.f;
            #pragma unroll
            for (int c = 0; c < NCLS; ++c) ssum += __expf(v[c] - m);
            float lse = m + __logf(ssum);
            #pragma unroll
            for (int c = 0; c < NCLS; ++c) out[(size_t)n2 * NCLS + c] = v[c] - lse;
        }
    }
}

extern "C" void kernel_launch(void* const* d_in, const int* in_sizes, int n_in,
                              void* d_out, int out_size, void* d_ws, size_t ws_size,
                              hipStream_t stream) {
    const float* x  = (const float*)d_in[0];
    const int*   ei = (const int*)d_in[1];
    const float* W1 = (const float*)d_in[2];
    const float* b1 = (const float*)d_in[3];
    const float* W2 = (const float*)d_in[4];
    const float* b2 = (const float*)d_in[5];
    float* out = (float*)d_out;

    const int N = in_sizes[0] / F_IN;        // 100000
    const int E = in_sizes[1] / 2;           // 3200000
    const int* row = ei;                     // source
    const int* col = ei + E;                 // target

    const int NB = (N + BS - 1) / BS;        // 782 buckets

    char* ws = (char*)d_ws;
    auto alignup = [](size_t v) { return (v + 255) & ~(size_t)255; };
    size_t offb = 0;
    int*   cnt  = (int*)  (ws + offb); offb += alignup((size_t)N * 4);
    int*   off  = (int*)  (ws + offb); offb += alignup((size_t)(N + 1) * 4);
    int*   bsum = (int*)  (ws + offb); offb += alignup(1024 * 4);
    int*   curb = (int*)  (ws + offb); offb += alignup((size_t)NB * 4);
    float* dinv = (float*)(ws + offb); offb += alignup((size_t)N * 4);
    unsigned int* pairs = (unsigned int*)(ws + offb); offb += alignup((size_t)E * 4);
    int*   srow = (int*)  (ws + offb); offb += alignup((size_t)E * 4);
    float* xws  = (float*)(ws + offb); offb += alignup((size_t)N * HID * 4);
    float* hs   = (float*)(ws + offb); offb += alignup((size_t)N * HID * 4);
    (void)ws_size; (void)n_in; (void)out_size;

    const int nb = (N + 1023) / 1024;        // scan blocks (<=128)

    hipMemsetAsync(cnt, 0, (size_t)N * sizeof(int), stream);
    hipMemsetAsync(curb, 0, (size_t)NB * sizeof(int), stream);
    k_hist <<<(E + 255) / 256, 256, 0, stream>>>(col, cnt, E);
    k_dinv <<<(N + 255) / 256, 256, 0, stream>>>(cnt, dinv, N);
    k_xw   <<<(N + 15) / 16, 256, 0, stream>>>(x, W1, dinv, xws, N);
    k_scanA<<<nb, 256, 0, stream>>>(cnt, off, bsum, N);
    k_scanB<<<1, 128, 0, stream>>>(bsum, nb);
    k_scanC<<<(N + 255) / 256, 256, 0, stream>>>(off, bsum, N, E);
    k_bin  <<<(E + 255) / 256, 256, 0, stream>>>(row, col, off, curb, pairs, E);
    k_place<<<NB, 256, 0, stream>>>(pairs, off, srow, N, E);
    k_agg1 <<<(N * HID + 255) / 256, 256, 0, stream>>>(xws, off, srow, dinv, b1, hs, N);
    k_agg2 <<<(N + 15) / 16, 256, 0, stream>>>(hs, off, srow, dinv, W2, b2, out, N);
}

// Round 4
// 801.904 us; speedup vs baseline: 1.2970x; 1.2970x over previous
//
#include <hip/hip_runtime.h>
#include <math.h>

#define F_IN 128
#define HID  16
#define NCLS 10
#define BS   128                 // nodes per bucket (pow2)
#define NB   782                 // ceil(100000/128); recomputed at launch
#define CH   16384               // edges per binning block

typedef unsigned int uint;

// ---------- pass A: per-bucket histogram (LDS local, 1 global add per block/bucket) ----------
__global__ void k_bhist(const int* __restrict__ col, int* __restrict__ bcnt, int E, int nbv) {
    extern __shared__ int hist[];
    int t = threadIdx.x;
    for (int i = t; i < nbv; i += 256) hist[i] = 0;
    __syncthreads();
    int start = blockIdx.x * CH, end = min(start + CH, E);
    for (int i = start + t; i < end; i += 256) atomicAdd(&hist[col[i] >> 7], 1);
    __syncthreads();
    for (int i = t; i < nbv; i += 256) if (hist[i]) atomicAdd(&bcnt[i], hist[i]);
}

// ---------- scan bucket counts -> boff (region bounds) + gcur (working cursors) ----------
__global__ void k_bscan(const int* __restrict__ bcnt, int* __restrict__ boff,
                        int* __restrict__ gcur, int nbv, int E) {
    __shared__ int s[1024];
    int t = threadIdx.x;
    int v = (t < nbv) ? bcnt[t] : 0;
    s[t] = v;
    __syncthreads();
    for (int ofs = 1; ofs < 1024; ofs <<= 1) {
        int val = (t >= ofs) ? s[t - ofs] : 0;
        __syncthreads();
        if (t >= ofs) s[t] += val;
        __syncthreads();
    }
    int excl = s[t] - v;
    if (t < nbv) { boff[t] = excl; gcur[t] = excl; }
    if (t == nbv) boff[t] = E;
}

// ---------- pass B: bin edges; block reserves contiguous run per bucket ----------
__global__ void k_bin(const int* __restrict__ row, const int* __restrict__ col,
                      int* __restrict__ gcur, uint* __restrict__ pairs, int E, int nbv) {
    extern __shared__ int lds[];          // hist | gbase | cur  (3 * nbv ints)
    int* hist  = lds;
    int* gbase = lds + nbv;
    int* cur   = lds + 2 * nbv;
    int t = threadIdx.x;
    for (int i = t; i < nbv; i += 256) { hist[i] = 0; cur[i] = 0; }
    __syncthreads();
    int start = blockIdx.x * CH, end = min(start + CH, E);
    for (int i = start + t; i < end; i += 256) atomicAdd(&hist[col[i] >> 7], 1);
    __syncthreads();
    for (int i = t; i < nbv; i += 256) gbase[i] = hist[i] ? atomicAdd(&gcur[i], hist[i]) : 0;
    __syncthreads();
    for (int i = start + t; i < end; i += 256) {
        int c = col[i];
        int b = c >> 7;
        int rk = atomicAdd(&cur[b], 1);
        pairs[gbase[b] + rk] = ((uint)row[i] << 7) | (uint)(c & (BS - 1));
    }
}

// ---------- per-node degree from pairs (LDS counters) -> dinv ----------
__global__ void k_ncnt(const uint* __restrict__ pairs, const int* __restrict__ boff,
                       float* __restrict__ dinv, int N) {
    __shared__ int cnt[BS];
    int b = blockIdx.x, t = threadIdx.x;
    if (t < BS) cnt[t] = 0;
    __syncthreads();
    int s = boff[b], e = boff[b + 1];
    for (int i = s + t; i < e; i += 256) atomicAdd(&cnt[pairs[i] & (BS - 1)], 1);
    __syncthreads();
    int n = b * BS + t;
    if (t < BS && n < N) dinv[n] = rsqrtf((float)cnt[t] + 1.0f);
}

// ---------- xw_s = dinv[n] * (x @ W1)  (128 -> 16) ----------
__global__ void k_xw(const float* __restrict__ x, const float* __restrict__ W1,
                     const float* __restrict__ dinv, float* __restrict__ xws, int N) {
    __shared__ float Ws[F_IN * HID];
    __shared__ float xs[16 * (F_IN + 1)];
    int t = threadIdx.x;
    for (int i = t; i < F_IN * HID; i += 256) Ws[i] = W1[i];
    int base = blockIdx.x * 16;
    for (int i = t; i < 16 * F_IN; i += 256) {
        int n = i >> 7, k = i & (F_IN - 1);
        xs[n * (F_IN + 1) + k] = (base + n < N) ? x[(size_t)(base + n) * F_IN + k] : 0.f;
    }
    __syncthreads();
    int n = t >> 4, h = t & 15;
    if (base + n >= N) return;
    const float* xr = xs + n * (F_IN + 1);
    float acc = 0.f;
    #pragma unroll
    for (int k = 0; k < F_IN; ++k) acc += xr[k] * Ws[k * HID + h];
    xws[(size_t)(base + n) * HID + h] = dinv[base + n] * acc;
}

// ---------- layer-1: stream bucket pairs, gather xws, LDS-accumulate, relu ----------
__global__ void k_agg1f(const uint* __restrict__ pairs, const int* __restrict__ boff,
                        const float* __restrict__ xws, const float* __restrict__ dinv,
                        const float* __restrict__ b1, float* __restrict__ hs, int N) {
    __shared__ float acc[BS * HID];       // 8 KB
    __shared__ float b1s[HID];
    int b = blockIdx.x, t = threadIdx.x;
    int cbase = b * BS;
    if (t < HID) b1s[t] = b1[t];
    for (int i = t; i < BS * HID; i += 256) {
        int n = cbase + (i >> 4);
        acc[i] = (n < N) ? xws[(size_t)n * HID + (i & 15)] : 0.f;   // self loop
    }
    __syncthreads();
    int s = boff[b], e = boff[b + 1];
    int g = t >> 4, l = t & 15;
    int i = s + g;
    for (; i + 48 < e; i += 64) {
        uint p0 = pairs[i], p1 = pairs[i + 16], p2 = pairs[i + 32], p3 = pairs[i + 48];
        float v0 = xws[(size_t)(p0 >> 7) * HID + l];
        float v1 = xws[(size_t)(p1 >> 7) * HID + l];
        float v2 = xws[(size_t)(p2 >> 7) * HID + l];
        float v3 = xws[(size_t)(p3 >> 7) * HID + l];
        atomicAdd(&acc[(p0 & (BS - 1)) * HID + l], v0);
        atomicAdd(&acc[(p1 & (BS - 1)) * HID + l], v1);
        atomicAdd(&acc[(p2 & (BS - 1)) * HID + l], v2);
        atomicAdd(&acc[(p3 & (BS - 1)) * HID + l], v3);
    }
    for (; i < e; i += 16) {
        uint p = pairs[i];
        atomicAdd(&acc[(p & (BS - 1)) * HID + l], xws[(size_t)(p >> 7) * HID + l]);
    }
    __syncthreads();
    int n = cbase + (t & 127);
    if (n < N) {
        float d = dinv[n];
        int half = t >> 7;
        #pragma unroll
        for (int j = 0; j < 8; ++j) {
            int jj = half * 8 + j;
            float h = d * acc[(t & 127) * HID + jj] + b1s[jj];
            h = h > 0.f ? h : 0.f;
            hs[(size_t)n * HID + jj] = d * h;
        }
    }
}

// ---------- layer-2: stream bucket pairs, gather hs, LDS-accumulate, W2+log_softmax ----------
__global__ void k_agg2f(const uint* __restrict__ pairs, const int* __restrict__ boff,
                        const float* __restrict__ hs, const float* __restrict__ dinv,
                        const float* __restrict__ W2, const float* __restrict__ b2,
                        float* __restrict__ out, int N) {
    __shared__ float acc[BS * HID];
    __shared__ float W2s[HID * NCLS];
    __shared__ float b2s[NCLS];
    int b = blockIdx.x, t = threadIdx.x;
    int cbase = b * BS;
    if (t < HID * NCLS) W2s[t] = W2[t];
    if (t < NCLS) b2s[t] = b2[t];
    for (int i = t; i < BS * HID; i += 256) {
        int n = cbase + (i >> 4);
        acc[i] = (n < N) ? hs[(size_t)n * HID + (i & 15)] : 0.f;    // self loop
    }
    __syncthreads();
    int s = boff[b], e = boff[b + 1];
    int g = t >> 4, l = t & 15;
    int i = s + g;
    for (; i + 48 < e; i += 64) {
        uint p0 = pairs[i], p1 = pairs[i + 16], p2 = pairs[i + 32], p3 = pairs[i + 48];
        float v0 = hs[(size_t)(p0 >> 7) * HID + l];
        float v1 = hs[(size_t)(p1 >> 7) * HID + l];
        float v2 = hs[(size_t)(p2 >> 7) * HID + l];
        float v3 = hs[(size_t)(p3 >> 7) * HID + l];
        atomicAdd(&acc[(p0 & (BS - 1)) * HID + l], v0);
        atomicAdd(&acc[(p1 & (BS - 1)) * HID + l], v1);
        atomicAdd(&acc[(p2 & (BS - 1)) * HID + l], v2);
        atomicAdd(&acc[(p3 & (BS - 1)) * HID + l], v3);
    }
    for (; i < e; i += 16) {
        uint p = pairs[i];
        atomicAdd(&acc[(p & (BS - 1)) * HID + l], hs[(size_t)(p >> 7) * HID + l]);
    }
    __syncthreads();
    if (t < BS) {
        int n = cbase + t;
        if (n < N) {
            float d = dinv[n];
            float v[NCLS];
            float m = -INFINITY;
            #pragma unroll
            for (int c = 0; c < NCLS; ++c) {
                float a = b2s[c];
                #pragma unroll
                for (int j = 0; j < HID; ++j) a += d * acc[t * HID + j] * W2s[j * NCLS + c];
                v[c] = a;
                m = fmaxf(m, a);
            }
            float ssum = 0.f;
            #pragma unroll
            for (int c = 0; c < NCLS; ++c) ssum += __expf(v[c] - m);
            float lse = m + __logf(ssum);
            #pragma unroll
            for (int c = 0; c < NCLS; ++c) out[(size_t)n * NCLS + c] = v[c] - lse;
        }
    }
}

extern "C" void kernel_launch(void* const* d_in, const int* in_sizes, int n_in,
                              void* d_out, int out_size, void* d_ws, size_t ws_size,
                              hipStream_t stream) {
    const float* x  = (const float*)d_in[0];
    const int*   ei = (const int*)d_in[1];
    const float* W1 = (const float*)d_in[2];
    const float* b1 = (const float*)d_in[3];
    const float* W2 = (const float*)d_in[4];
    const float* b2 = (const float*)d_in[5];
    float* out = (float*)d_out;

    const int N = in_sizes[0] / F_IN;        // 100000
    const int E = in_sizes[1] / 2;           // 3200000
    const int* row = ei;                     // source
    const int* col = ei + E;                 // target

    const int nbv = (N + BS - 1) / BS;       // 782 buckets
    const int nchunk = (E + CH - 1) / CH;    // 196 binning blocks

    char* ws = (char*)d_ws;
    auto alignup = [](size_t v) { return (v + 255) & ~(size_t)255; };
    size_t offb = 0;
    int*   bcnt = (int*)  (ws + offb); offb += alignup((size_t)(nbv + 1) * 4);
    int*   boff = (int*)  (ws + offb); offb += alignup((size_t)(nbv + 1) * 4);
    int*   gcur = (int*)  (ws + offb); offb += alignup((size_t)(nbv + 1) * 4);
    float* dinv = (float*)(ws + offb); offb += alignup((size_t)N * 4);
    uint*  pairs= (uint*) (ws + offb); offb += alignup((size_t)E * 4);
    float* xws  = (float*)(ws + offb); offb += alignup((size_t)N * HID * 4);
    float* hs   = (float*)(ws + offb); offb += alignup((size_t)N * HID * 4);
    (void)ws_size; (void)n_in; (void)out_size;

    size_t histB = (size_t)nbv * 4;

    hipMemsetAsync(bcnt, 0, (size_t)(nbv + 1) * sizeof(int), stream);
    k_bhist<<<nchunk, 256, histB,     stream>>>(col, bcnt, E, nbv);
    k_bscan<<<1, 1024, 0,             stream>>>(bcnt, boff, gcur, nbv, E);
    k_bin  <<<nchunk, 256, 3 * histB, stream>>>(row, col, gcur, pairs, E, nbv);
    k_ncnt <<<nbv, 256, 0,            stream>>>(pairs, boff, dinv, N);
    k_xw   <<<(N + 15) / 16, 256, 0,  stream>>>(x, W1, dinv, xws, N);
    k_agg1f<<<nbv, 256, 0,            stream>>>(pairs, boff, xws, dinv, b1, hs, N);
    k_agg2f<<<nbv, 256, 0,            stream>>>(pairs, boff, hs, dinv, W2, b2, out, N);
}

// Round 5
// 235.921 us; speedup vs baseline: 4.4084x; 3.3990x over previous
//
#include <hip/hip_runtime.h>
#include <math.h>

#define F_IN 128
#define HID  16
#define NCLS 10
#define BS   128                 // nodes per bucket (pow2)
#define CH   16384               // edges per binning block

typedef unsigned int uint;

// ---------- pass A: per-bucket histogram (LDS local) ----------
__global__ void k_bhist(const int* __restrict__ col, int* __restrict__ bcnt, int E, int nbv) {
    extern __shared__ int hist[];
    int t = threadIdx.x;
    for (int i = t; i < nbv; i += 256) hist[i] = 0;
    __syncthreads();
    int start = blockIdx.x * CH, end = min(start + CH, E);
    for (int i = start + t; i < end; i += 256) atomicAdd(&hist[col[i] >> 7], 1);
    __syncthreads();
    for (int i = t; i < nbv; i += 256) if (hist[i]) atomicAdd(&bcnt[i], hist[i]);
}

// ---------- scan bucket counts -> boff + working cursors ----------
__global__ void k_bscan(const int* __restrict__ bcnt, int* __restrict__ boff,
                        int* __restrict__ gcur, int nbv, int E) {
    __shared__ int s[1024];
    int t = threadIdx.x;
    int v = (t < nbv) ? bcnt[t] : 0;
    s[t] = v;
    __syncthreads();
    for (int ofs = 1; ofs < 1024; ofs <<= 1) {
        int val = (t >= ofs) ? s[t - ofs] : 0;
        __syncthreads();
        if (t >= ofs) s[t] += val;
        __syncthreads();
    }
    int excl = s[t] - v;
    if (t < nbv) { boff[t] = excl; gcur[t] = excl; }
    if (t == nbv) boff[t] = E;
}

// ---------- pass B: bin edges; block reserves contiguous run per bucket ----------
__global__ void k_bin(const int* __restrict__ row, const int* __restrict__ col,
                      int* __restrict__ gcur, uint* __restrict__ pairs, int E, int nbv) {
    extern __shared__ int lds[];          // hist | gbase | cur
    int* hist  = lds;
    int* gbase = lds + nbv;
    int* cur   = lds + 2 * nbv;
    int t = threadIdx.x;
    for (int i = t; i < nbv; i += 256) { hist[i] = 0; cur[i] = 0; }
    __syncthreads();
    int start = blockIdx.x * CH, end = min(start + CH, E);
    for (int i = start + t; i < end; i += 256) atomicAdd(&hist[col[i] >> 7], 1);
    __syncthreads();
    for (int i = t; i < nbv; i += 256) gbase[i] = hist[i] ? atomicAdd(&gcur[i], hist[i]) : 0;
    __syncthreads();
    for (int i = start + t; i < end; i += 256) {
        int c = col[i];
        int b = c >> 7;
        int rk = atomicAdd(&cur[b], 1);
        pairs[gbase[b] + rk] = ((uint)row[i] << 7) | (uint)(c & (BS - 1));
    }
}

// ---------- per-node counts from pairs (LDS) -> cnt (int) + dinv ----------
__global__ void k_ncnt(const uint* __restrict__ pairs, const int* __restrict__ boff,
                       int* __restrict__ cnt, float* __restrict__ dinv, int N) {
    __shared__ int c[BS];
    int b = blockIdx.x, t = threadIdx.x;
    if (t < BS) c[t] = 0;
    __syncthreads();
    int s = boff[b], e = boff[b + 1];
    for (int i = s + t; i < e; i += 256) atomicAdd(&c[pairs[i] & (BS - 1)], 1);
    __syncthreads();
    int n = b * BS + t;
    if (t < BS && n < N) {
        cnt[n] = c[t];
        dinv[n] = rsqrtf((float)c[t] + 1.0f);
    }
}

// ---------- exclusive scan over cnt -> off ----------
__global__ void k_scanA(const int* __restrict__ cnt, int* __restrict__ off,
                        int* __restrict__ bsum, int N) {
    __shared__ int s[256];
    int b = blockIdx.x, t = threadIdx.x;
    int base = b * 1024 + t * 4;
    int v[4], sum = 0;
    #pragma unroll
    for (int i = 0; i < 4; ++i) { int idx = base + i; v[i] = (idx < N) ? cnt[idx] : 0; sum += v[i]; }
    s[t] = sum;
    __syncthreads();
    for (int ofs = 1; ofs < 256; ofs <<= 1) {
        int val = (t >= ofs) ? s[t - ofs] : 0;
        __syncthreads();
        if (t >= ofs) s[t] += val;
        __syncthreads();
    }
    int excl = s[t] - sum;
    if (t == 255) bsum[b] = s[255];
    int run = excl;
    #pragma unroll
    for (int i = 0; i < 4; ++i) { int idx = base + i; if (idx < N) off[idx] = run; run += v[i]; }
}

__global__ void k_scanB(int* __restrict__ bsum, int nb) {
    __shared__ int s[128];
    int t = threadIdx.x;
    int v = (t < nb) ? bsum[t] : 0;
    s[t] = v;
    __syncthreads();
    for (int ofs = 1; ofs < 128; ofs <<= 1) {
        int val = (t >= ofs) ? s[t - ofs] : 0;
        __syncthreads();
        if (t >= ofs) s[t] += val;
        __syncthreads();
    }
    if (t < nb) bsum[t] = s[t] - v;   // exclusive
}

__global__ void k_scanC(int* __restrict__ off, const int* __restrict__ bsum, int N, int E) {
    int i = blockIdx.x * blockDim.x + threadIdx.x;
    if (i < N) off[i] += bsum[i >> 10];
    if (i == 0) off[N] = E;
}

// ---------- place: per bucket, LDS cursors -> srow (writes stay in ~16KB window) ----------
__global__ void k_place(const uint* __restrict__ pairs, const int* __restrict__ boff,
                        const int* __restrict__ off, int* __restrict__ srow, int N) {
    __shared__ int so[BS];
    __shared__ int cu[BS];
    int b = blockIdx.x, t = threadIdx.x;
    int cbase = b << 7;
    if (t < BS) {
        so[t] = (cbase + t < N) ? off[cbase + t] : 0;
        cu[t] = 0;
    }
    __syncthreads();
    int s = boff[b], e = boff[b + 1];
    for (int i = s + t; i < e; i += 256) {
        uint v = pairs[i];
        int cl = v & (BS - 1);
        int p = so[cl] + atomicAdd(&cu[cl], 1);
        srow[p] = (int)(v >> 7);
    }
}

// ---------- xw_s = dinv[n] * (x @ W1)  (128 -> 16) ----------
__global__ void k_xw(const float* __restrict__ x, const float* __restrict__ W1,
                     const float* __restrict__ dinv, float* __restrict__ xws, int N) {
    __shared__ float Ws[F_IN * HID];
    __shared__ float xs[16 * (F_IN + 1)];
    int t = threadIdx.x;
    for (int i = t; i < F_IN * HID; i += 256) Ws[i] = W1[i];
    int base = blockIdx.x * 16;
    for (int i = t; i < 16 * F_IN; i += 256) {
        int n = i >> 7, k = i & (F_IN - 1);
        xs[n * (F_IN + 1) + k] = (base + n < N) ? x[(size_t)(base + n) * F_IN + k] : 0.f;
    }
    __syncthreads();
    int n = t >> 4, h = t & 15;
    if (base + n >= N) return;
    const float* xr = xs + n * (F_IN + 1);
    float acc = 0.f;
    #pragma unroll
    for (int k = 0; k < F_IN; ++k) acc += xr[k] * Ws[k * HID + h];
    xws[(size_t)(base + n) * HID + h] = dinv[base + n] * acc;
}

// ---------- layer-1 pull: hs = dinv * relu(dinv*sum + b1) ----------
__global__ void k_agg1(const float* __restrict__ xws, const int* __restrict__ off,
                       const int* __restrict__ srow, const float* __restrict__ dinv,
                       const float* __restrict__ b1, float* __restrict__ hs, int N) {
    int n = (blockIdx.x * blockDim.x + threadIdx.x) >> 4;
    int l = threadIdx.x & 15;
    if (n >= N) return;
    int s = off[n], e = off[n + 1];
    float a0 = xws[(size_t)n * HID + l];   // self loop (dinv-scaled)
    float a1 = 0.f, a2 = 0.f, a3 = 0.f;
    int i = s;
    for (; i + 7 < e; i += 8) {
        int r0 = srow[i],     r1 = srow[i + 1], r2 = srow[i + 2], r3 = srow[i + 3];
        int r4 = srow[i + 4], r5 = srow[i + 5], r6 = srow[i + 6], r7 = srow[i + 7];
        a0 += xws[(size_t)r0 * HID + l]; a1 += xws[(size_t)r1 * HID + l];
        a2 += xws[(size_t)r2 * HID + l]; a3 += xws[(size_t)r3 * HID + l];
        a0 += xws[(size_t)r4 * HID + l]; a1 += xws[(size_t)r5 * HID + l];
        a2 += xws[(size_t)r6 * HID + l]; a3 += xws[(size_t)r7 * HID + l];
    }
    for (; i < e; ++i) a0 += xws[(size_t)srow[i] * HID + l];
    float acc = (a0 + a1) + (a2 + a3);
    float d = dinv[n];
    float h = d * acc + b1[l];
    h = h > 0.f ? h : 0.f;
    hs[(size_t)n * HID + l] = d * h;
}

// ---------- layer-2 pull + fused W2/b2/log_softmax ----------
__global__ void k_agg2(const float* __restrict__ hs, const int* __restrict__ off,
                       const int* __restrict__ srow, const float* __restrict__ dinv,
                       const float* __restrict__ W2, const float* __restrict__ b2,
                       float* __restrict__ out, int N) {
    __shared__ float gs[16][17];
    __shared__ float W2s[HID * NCLS];
    __shared__ float b2s[NCLS];
    int t = threadIdx.x;
    if (t < HID * NCLS) W2s[t] = W2[t];
    if (t < NCLS) b2s[t] = b2[t];
    int grp = t >> 4, l = t & 15;
    int n = blockIdx.x * 16 + grp;
    float g = 0.f;
    if (n < N) {
        int s = off[n], e = off[n + 1];
        float a0 = hs[(size_t)n * HID + l];
        float a1 = 0.f, a2 = 0.f, a3 = 0.f;
        int i = s;
        for (; i + 7 < e; i += 8) {
            int r0 = srow[i],     r1 = srow[i + 1], r2 = srow[i + 2], r3 = srow[i + 3];
            int r4 = srow[i + 4], r5 = srow[i + 5], r6 = srow[i + 6], r7 = srow[i + 7];
            a0 += hs[(size_t)r0 * HID + l]; a1 += hs[(size_t)r1 * HID + l];
            a2 += hs[(size_t)r2 * HID + l]; a3 += hs[(size_t)r3 * HID + l];
            a0 += hs[(size_t)r4 * HID + l]; a1 += hs[(size_t)r5 * HID + l];
            a2 += hs[(size_t)r6 * HID + l]; a3 += hs[(size_t)r7 * HID + l];
        }
        for (; i < e; ++i) a0 += hs[(size_t)srow[i] * HID + l];
        g = dinv[n] * ((a0 + a1) + (a2 + a3));
    }
    gs[grp][l] = g;
    __syncthreads();
    if (t < 16) {
        int n2 = blockIdx.x * 16 + t;
        if (n2 < N) {
            float v[NCLS];
            float m = -INFINITY;
            #pragma unroll
            for (int c = 0; c < NCLS; ++c) {
                float a = b2s[c];
                #pragma unroll
                for (int j = 0; j < HID; ++j) a += gs[t][j] * W2s[j * NCLS + c];
                v[c] = a;
                m = fmaxf(m, a);
            }
            float ssum = 0.f;
            #pragma unroll
            for (int c = 0; c < NCLS; ++c) ssum += __expf(v[c] - m);
            float lse = m + __logf(ssum);
            #pragma unroll
            for (int c = 0; c < NCLS; ++c) out[(size_t)n2 * NCLS + c] = v[c] - lse;
        }
    }
}

extern "C" void kernel_launch(void* const* d_in, const int* in_sizes, int n_in,
                              void* d_out, int out_size, void* d_ws, size_t ws_size,
                              hipStream_t stream) {
    const float* x  = (const float*)d_in[0];
    const int*   ei = (const int*)d_in[1];
    const float* W1 = (const float*)d_in[2];
    const float* b1 = (const float*)d_in[3];
    const float* W2 = (const float*)d_in[4];
    const float* b2 = (const float*)d_in[5];
    float* out = (float*)d_out;

    const int N = in_sizes[0] / F_IN;        // 100000
    const int E = in_sizes[1] / 2;           // 3200000
    const int* row = ei;                     // source
    const int* col = ei + E;                 // target

    const int nbv = (N + BS - 1) / BS;       // 782 buckets
    const int nchunk = (E + CH - 1) / CH;    // 196 binning blocks
    const int nsb = (N + 1023) / 1024;       // scan blocks (98)

    char* ws = (char*)d_ws;
    auto alignup = [](size_t v) { return (v + 255) & ~(size_t)255; };
    size_t offb = 0;
    int*   bcnt = (int*)  (ws + offb); offb += alignup((size_t)(nbv + 1) * 4);
    int*   boff = (int*)  (ws + offb); offb += alignup((size_t)(nbv + 1) * 4);
    int*   gcur = (int*)  (ws + offb); offb += alignup((size_t)(nbv + 1) * 4);
    int*   cnt  = (int*)  (ws + offb); offb += alignup((size_t)N * 4);
    int*   off  = (int*)  (ws + offb); offb += alignup((size_t)(N + 1) * 4);
    int*   bsum = (int*)  (ws + offb); offb += alignup(1024 * 4);
    float* dinv = (float*)(ws + offb); offb += alignup((size_t)N * 4);
    uint*  pairs= (uint*) (ws + offb); offb += alignup((size_t)E * 4);
    int*   srow = (int*)  (ws + offb); offb += alignup((size_t)E * 4);
    float* xws  = (float*)(ws + offb); offb += alignup((size_t)N * HID * 4);
    float* hs   = (float*)(ws + offb); offb += alignup((size_t)N * HID * 4);
    (void)ws_size; (void)n_in; (void)out_size;

    size_t histB = (size_t)nbv * 4;

    hipMemsetAsync(bcnt, 0, (size_t)(nbv + 1) * sizeof(int), stream);
    k_bhist<<<nchunk, 256, histB,     stream>>>(col, bcnt, E, nbv);
    k_bscan<<<1, 1024, 0,             stream>>>(bcnt, boff, gcur, nbv, E);
    k_bin  <<<nchunk, 256, 3 * histB, stream>>>(row, col, gcur, pairs, E, nbv);
    k_ncnt <<<nbv, 256, 0,            stream>>>(pairs, boff, cnt, dinv, N);
    k_xw   <<<(N + 15) / 16, 256, 0,  stream>>>(x, W1, dinv, xws, N);
    k_scanA<<<nsb, 256, 0,            stream>>>(cnt, off, bsum, N);
    k_scanB<<<1, 128, 0,              stream>>>(bsum, nsb);
    k_scanC<<<(N + 255) / 256, 256, 0,stream>>>(off, bsum, N, E);
    k_place<<<nbv, 256, 0,            stream>>>(pairs, boff, off, srow, N);
    k_agg1 <<<(N * HID + 255) / 256, 256, 0, stream>>>(xws, off, srow, dinv, b1, hs, N);
    k_agg2 <<<(N + 15) / 16, 256, 0,  stream>>>(hs, off, srow, dinv, W2, b2, out, N);
}

// Round 6
// 205.943 us; speedup vs baseline: 5.0501x; 1.1456x over previous
//
#include <hip/hip_runtime.h>
#include <math.h>

#define F_IN 128
#define HID  16
#define NCLS 10
#define BS   128                 // nodes per bucket (pow2)
#define CH   8192                // edges per binning chunk
#define KPL  8                   // chunks per lane in k_cscan (supports <=512 chunks)

typedef unsigned int uint;

// ---------- chunk x bucket histogram matrix (atomic-free reservation) ----------
// block k: LDS hist of its chunk, write row hist[k*nbv + b] (coalesced).
__global__ void k_hist2(const int* __restrict__ col, int* __restrict__ hist, int E, int nbv) {
    extern __shared__ int h[];
    int t = threadIdx.x, k = blockIdx.x;
    for (int i = t; i < nbv; i += 256) h[i] = 0;
    __syncthreads();
    int start = k * CH, end = min(start + CH, E);
    for (int i = start + t; i < end; i += 256) atomicAdd(&h[col[i] >> 7], 1);
    __syncthreads();
    for (int i = t; i < nbv; i += 256) hist[(size_t)k * nbv + i] = h[i];
}

// ---------- column scan: one wave per bucket, exclusive prefix across chunks ----------
// in-place hist[k][b] -> sum_{k'<k} hist[k'][b]; bucket total -> bcnt[b]
__global__ void k_cscan(int* __restrict__ hist, int* __restrict__ bcnt, int nchunk, int nbv) {
    int wave = threadIdx.x >> 6, lane = threadIdx.x & 63;
    int b = blockIdx.x * 4 + wave;
    if (b >= nbv) return;
    int vals[KPL];
    int ls = 0;
    #pragma unroll
    for (int i = 0; i < KPL; ++i) {
        int k = lane * KPL + i;
        vals[i] = (k < nchunk) ? hist[(size_t)k * nbv + b] : 0;
        ls += vals[i];
    }
    int inc = ls;
    #pragma unroll
    for (int d = 1; d < 64; d <<= 1) {
        int v = __shfl_up(inc, d, 64);
        if (lane >= d) inc += v;
    }
    int run = inc - ls;                      // exclusive lane base
    #pragma unroll
    for (int i = 0; i < KPL; ++i) {
        int k = lane * KPL + i;
        if (k < nchunk) { hist[(size_t)k * nbv + b] = run; run += vals[i]; }
    }
    int total = __shfl(inc, 63, 64);         // inclusive at last lane = grand total
    if (lane == 0) bcnt[b] = total;
}

// ---------- scan bucket totals -> boff ----------
__global__ void k_bscan(const int* __restrict__ bcnt, int* __restrict__ boff, int nbv, int E) {
    __shared__ int s[1024];
    int t = threadIdx.x;
    int v = (t < nbv) ? bcnt[t] : 0;
    s[t] = v;
    __syncthreads();
    for (int ofs = 1; ofs < 1024; ofs <<= 1) {
        int val = (t >= ofs) ? s[t - ofs] : 0;
        __syncthreads();
        if (t >= ofs) s[t] += val;
        __syncthreads();
    }
    if (t < nbv) boff[t] = s[t] - v;
    if (t == nbv) boff[t] = E;
}

// ---------- bin: place edges via precomputed bases + LDS cursors only ----------
__global__ void k_binW(const int* __restrict__ row, const int* __restrict__ col,
                       const int* __restrict__ hist, const int* __restrict__ boff,
                       uint* __restrict__ pairs, int E, int nbv) {
    extern __shared__ int lds[];          // gbase | cur
    int* gbase = lds;
    int* cur   = lds + nbv;
    int t = threadIdx.x, k = blockIdx.x;
    for (int i = t; i < nbv; i += 256) {
        gbase[i] = boff[i] + hist[(size_t)k * nbv + i];
        cur[i] = 0;
    }
    __syncthreads();
    int start = k * CH, end = min(start + CH, E);
    for (int i = start + t; i < end; i += 256) {
        int c = col[i];
        int b = c >> 7;
        int rk = atomicAdd(&cur[b], 1);
        pairs[gbase[b] + rk] = ((uint)row[i] << 7) | (uint)(c & (BS - 1));
    }
}

// ---------- per-node counts from pairs (LDS) -> cnt + dinv ----------
__global__ void k_ncnt(const uint* __restrict__ pairs, const int* __restrict__ boff,
                       int* __restrict__ cnt, float* __restrict__ dinv, int N) {
    __shared__ int c[BS];
    int b = blockIdx.x, t = threadIdx.x;
    if (t < BS) c[t] = 0;
    __syncthreads();
    int s = boff[b], e = boff[b + 1];
    for (int i = s + t; i < e; i += 256) atomicAdd(&c[pairs[i] & (BS - 1)], 1);
    __syncthreads();
    int n = b * BS + t;
    if (t < BS && n < N) {
        cnt[n] = c[t];
        dinv[n] = rsqrtf((float)c[t] + 1.0f);
    }
}

// ---------- exclusive scan over cnt -> off ----------
__global__ void k_scanA(const int* __restrict__ cnt, int* __restrict__ off,
                        int* __restrict__ bsum, int N) {
    __shared__ int s[256];
    int b = blockIdx.x, t = threadIdx.x;
    int base = b * 1024 + t * 4;
    int v[4], sum = 0;
    #pragma unroll
    for (int i = 0; i < 4; ++i) { int idx = base + i; v[i] = (idx < N) ? cnt[idx] : 0; sum += v[i]; }
    s[t] = sum;
    __syncthreads();
    for (int ofs = 1; ofs < 256; ofs <<= 1) {
        int val = (t >= ofs) ? s[t - ofs] : 0;
        __syncthreads();
        if (t >= ofs) s[t] += val;
        __syncthreads();
    }
    int excl = s[t] - sum;
    if (t == 255) bsum[b] = s[255];
    int run = excl;
    #pragma unroll
    for (int i = 0; i < 4; ++i) { int idx = base + i; if (idx < N) off[idx] = run; run += v[i]; }
}

__global__ void k_scanB(int* __restrict__ bsum, int nb) {
    __shared__ int s[128];
    int t = threadIdx.x;
    int v = (t < nb) ? bsum[t] : 0;
    s[t] = v;
    __syncthreads();
    for (int ofs = 1; ofs < 128; ofs <<= 1) {
        int val = (t >= ofs) ? s[t - ofs] : 0;
        __syncthreads();
        if (t >= ofs) s[t] += val;
        __syncthreads();
    }
    if (t < nb) bsum[t] = s[t] - v;   // exclusive
}

__global__ void k_scanC(int* __restrict__ off, const int* __restrict__ bsum, int N, int E) {
    int i = blockIdx.x * blockDim.x + threadIdx.x;
    if (i < N) off[i] += bsum[i >> 10];
    if (i == 0) off[N] = E;
}

// ---------- place: per bucket, LDS cursors -> srow (writes stay in ~16KB window) ----------
__global__ void k_place(const uint* __restrict__ pairs, const int* __restrict__ boff,
                        const int* __restrict__ off, int* __restrict__ srow, int N) {
    __shared__ int so[BS];
    __shared__ int cu[BS];
    int b = blockIdx.x, t = threadIdx.x;
    int cbase = b << 7;
    if (t < BS) {
        so[t] = (cbase + t < N) ? off[cbase + t] : 0;
        cu[t] = 0;
    }
    __syncthreads();
    int s = boff[b], e = boff[b + 1];
    for (int i = s + t; i < e; i += 256) {
        uint v = pairs[i];
        int cl = v & (BS - 1);
        int p = so[cl] + atomicAdd(&cu[cl], 1);
        srow[p] = (int)(v >> 7);
    }
}

// ---------- xw_s = dinv[n] * (x @ W1)  (128 -> 16) ----------
__global__ void k_xw(const float* __restrict__ x, const float* __restrict__ W1,
                     const float* __restrict__ dinv, float* __restrict__ xws, int N) {
    __shared__ float Ws[F_IN * HID];
    __shared__ float xs[16 * (F_IN + 1)];
    int t = threadIdx.x;
    for (int i = t; i < F_IN * HID; i += 256) Ws[i] = W1[i];
    int base = blockIdx.x * 16;
    for (int i = t; i < 16 * F_IN; i += 256) {
        int n = i >> 7, k = i & (F_IN - 1);
        xs[n * (F_IN + 1) + k] = (base + n < N) ? x[(size_t)(base + n) * F_IN + k] : 0.f;
    }
    __syncthreads();
    int n = t >> 4, h = t & 15;
    if (base + n >= N) return;
    const float* xr = xs + n * (F_IN + 1);
    float acc = 0.f;
    #pragma unroll
    for (int k = 0; k < F_IN; ++k) acc += xr[k] * Ws[k * HID + h];
    xws[(size_t)(base + n) * HID + h] = dinv[base + n] * acc;
}

// ---------- layer-1 pull: hs = dinv * relu(dinv*sum + b1) ----------
__global__ void k_agg1(const float* __restrict__ xws, const int* __restrict__ off,
                       const int* __restrict__ srow, const float* __restrict__ dinv,
                       const float* __restrict__ b1, float* __restrict__ hs, int N) {
    int n = (blockIdx.x * blockDim.x + threadIdx.x) >> 4;
    int l = threadIdx.x & 15;
    if (n >= N) return;
    int s = off[n], e = off[n + 1];
    float a0 = xws[(size_t)n * HID + l];   // self loop (dinv-scaled)
    float a1 = 0.f, a2 = 0.f, a3 = 0.f;
    int i = s;
    for (; i + 7 < e; i += 8) {
        int r0 = srow[i],     r1 = srow[i + 1], r2 = srow[i + 2], r3 = srow[i + 3];
        int r4 = srow[i + 4], r5 = srow[i + 5], r6 = srow[i + 6], r7 = srow[i + 7];
        a0 += xws[(size_t)r0 * HID + l]; a1 += xws[(size_t)r1 * HID + l];
        a2 += xws[(size_t)r2 * HID + l]; a3 += xws[(size_t)r3 * HID + l];
        a0 += xws[(size_t)r4 * HID + l]; a1 += xws[(size_t)r5 * HID + l];
        a2 += xws[(size_t)r6 * HID + l]; a3 += xws[(size_t)r7 * HID + l];
    }
    for (; i < e; ++i) a0 += xws[(size_t)srow[i] * HID + l];
    float acc = (a0 + a1) + (a2 + a3);
    float d = dinv[n];
    float h = d * acc + b1[l];
    h = h > 0.f ? h : 0.f;
    hs[(size_t)n * HID + l] = d * h;
}

// ---------- layer-2 pull + fused W2/b2/log_softmax ----------
__global__ void k_agg2(const float* __restrict__ hs, const int* __restrict__ off,
                       const int* __restrict__ srow, const float* __restrict__ dinv,
                       const float* __restrict__ W2, const float* __restrict__ b2,
                       float* __restrict__ out, int N) {
    __shared__ float gs[16][17];
    __shared__ float W2s[HID * NCLS];
    __shared__ float b2s[NCLS];
    int t = threadIdx.x;
    if (t < HID * NCLS) W2s[t] = W2[t];
    if (t < NCLS) b2s[t] = b2[t];
    int grp = t >> 4, l = t & 15;
    int n = blockIdx.x * 16 + grp;
    float g = 0.f;
    if (n < N) {
        int s = off[n], e = off[n + 1];
        float a0 = hs[(size_t)n * HID + l];
        float a1 = 0.f, a2 = 0.f, a3 = 0.f;
        int i = s;
        for (; i + 7 < e; i += 8) {
            int r0 = srow[i],     r1 = srow[i + 1], r2 = srow[i + 2], r3 = srow[i + 3];
            int r4 = srow[i + 4], r5 = srow[i + 5], r6 = srow[i + 6], r7 = srow[i + 7];
            a0 += hs[(size_t)r0 * HID + l]; a1 += hs[(size_t)r1 * HID + l];
            a2 += hs[(size_t)r2 * HID + l]; a3 += hs[(size_t)r3 * HID + l];
            a0 += hs[(size_t)r4 * HID + l]; a1 += hs[(size_t)r5 * HID + l];
            a2 += hs[(size_t)r6 * HID + l]; a3 += hs[(size_t)r7 * HID + l];
        }
        for (; i < e; ++i) a0 += hs[(size_t)srow[i] * HID + l];
        g = dinv[n] * ((a0 + a1) + (a2 + a3));
    }
    gs[grp][l] = g;
    __syncthreads();
    if (t < 16) {
        int n2 = blockIdx.x * 16 + t;
        if (n2 < N) {
            float v[NCLS];
            float m = -INFINITY;
            #pragma unroll
            for (int c = 0; c < NCLS; ++c) {
                float a = b2s[c];
                #pragma unroll
                for (int j = 0; j < HID; ++j) a += gs[t][j] * W2s[j * NCLS + c];
                v[c] = a;
                m = fmaxf(m, a);
            }
            float ssum = 0.f;
            #pragma unroll
            for (int c = 0; c < NCLS; ++c) ssum += __expf(v[c] - m);
            float lse = m + __logf(ssum);
            #pragma unroll
            for (int c = 0; c < NCLS; ++c) out[(size_t)n2 * NCLS + c] = v[c] - lse;
        }
    }
}

extern "C" void kernel_launch(void* const* d_in, const int* in_sizes, int n_in,
                              void* d_out, int out_size, void* d_ws, size_t ws_size,
                              hipStream_t stream) {
    const float* x  = (const float*)d_in[0];
    const int*   ei = (const int*)d_in[1];
    const float* W1 = (const float*)d_in[2];
    const float* b1 = (const float*)d_in[3];
    const float* W2 = (const float*)d_in[4];
    const float* b2 = (const float*)d_in[5];
    float* out = (float*)d_out;

    const int N = in_sizes[0] / F_IN;        // 100000
    const int E = in_sizes[1] / 2;           // 3200000
    const int* row = ei;                     // source
    const int* col = ei + E;                 // target

    const int nbv = (N + BS - 1) / BS;       // 782 buckets
    const int nchunk = (E + CH - 1) / CH;    // 391 chunks (<= 64*KPL)
    const int nsb = (N + 1023) / 1024;       // node-scan blocks (98)

    char* ws = (char*)d_ws;
    auto alignup = [](size_t v) { return (v + 255) & ~(size_t)255; };
    size_t offb = 0;
    int*   hist = (int*)  (ws + offb); offb += alignup((size_t)nchunk * nbv * 4);  // ~1.2 MB
    int*   bcnt = (int*)  (ws + offb); offb += alignup((size_t)(nbv + 1) * 4);
    int*   boff = (int*)  (ws + offb); offb += alignup((size_t)(nbv + 1) * 4);
    int*   cnt  = (int*)  (ws + offb); offb += alignup((size_t)N * 4);
    int*   off  = (int*)  (ws + offb); offb += alignup((size_t)(N + 1) * 4);
    int*   bsum = (int*)  (ws + offb); offb += alignup(1024 * 4);
    float* dinv = (float*)(ws + offb); offb += alignup((size_t)N * 4);
    uint*  pairs= (uint*) (ws + offb); offb += alignup((size_t)E * 4);
    int*   srow = (int*)  (ws + offb); offb += alignup((size_t)E * 4);
    float* xws  = (float*)(ws + offb); offb += alignup((size_t)N * HID * 4);
    float* hs   = (float*)(ws + offb); offb += alignup((size_t)N * HID * 4);
    (void)ws_size; (void)n_in; (void)out_size;

    size_t histB = (size_t)nbv * 4;

    k_hist2<<<nchunk, 256, histB,     stream>>>(col, hist, E, nbv);
    k_cscan<<<(nbv + 3) / 4, 256, 0,  stream>>>(hist, bcnt, nchunk, nbv);
    k_bscan<<<1, 1024, 0,             stream>>>(bcnt, boff, nbv, E);
    k_binW <<<nchunk, 256, 2 * histB, stream>>>(row, col, hist, boff, pairs, E, nbv);
    k_ncnt <<<nbv, 256, 0,            stream>>>(pairs, boff, cnt, dinv, N);
    k_xw   <<<(N + 15) / 16, 256, 0,  stream>>>(x, W1, dinv, xws, N);
    k_scanA<<<nsb, 256, 0,            stream>>>(cnt, off, bsum, N);
    k_scanB<<<1, 128, 0,              stream>>>(bsum, nsb);
    k_scanC<<<(N + 255) / 256, 256, 0,stream>>>(off, bsum, N, E);
    k_place<<<nbv, 256, 0,            stream>>>(pairs, boff, off, srow, N);
    k_agg1 <<<(N * HID + 255) / 256, 256, 0, stream>>>(xws, off, srow, dinv, b1, hs, N);
    k_agg2 <<<(N + 15) / 16, 256, 0,  stream>>>(hs, off, srow, dinv, W2, b2, out, N);
}